// Round 11
// baseline (142.925 us; speedup 1.0000x reference)
//
#include <hip/hip_runtime.h>
#include <math.h>

#define BLOCK 256
#define TQ    512                 // quaternions per tile per array
#define CH    (TQ / BLOCK)        // 2 chunks of 256 elems per array
#define GRID  1280                // 5 blocks/CU * 256 CU (LDS-limited residency)

// theta^2 for rel = qinv(a) * idd.
// rel is (nearly) unit-norm, so atan2(|v|, w) == acos(w / |rel|).
// Hastings acos approx, max abs err ~6.8e-5 rad (tolerance is 2% relative).
__device__ __forceinline__ float theta_sq(float4 qa, float4 qb) {
    float w1 = qa.x, x1 = -qa.y, y1 = -qa.z, z1 = -qa.w;
    float w2 = qb.x, x2 = qb.y,  y2 = qb.z,  z2 = qb.w;
    float w  = w1*w2 - (x1*x2 + y1*y2 + z1*z2);
    float vx = w1*x2 + w2*x1 + (y1*z2 - z1*y2);
    float vy = w1*y2 + w2*y1 + (z1*x2 - x1*z2);
    float vz = w1*z2 + w2*z1 + (x1*y2 - y1*x2);
    float nv2 = vx*vx + vy*vy + vz*vz;
    if (nv2 < 1e-12f) {                  // reference small-angle branch (nv < 1e-6)
        float s = 2.0f / w;
        return nv2 * s * s;
    }
    float rn = rsqrtf(w*w + nv2);        // exact normalize (~1.0)
    float c  = w * rn;                   // cos(theta/2) in [-1,1]
    float ac = fabsf(c);
    float p  = ((-0.0187293f*ac + 0.0742610f)*ac - 0.2121144f)*ac + 1.5707288f;
    float r  = sqrtf(fmaxf(1.0f - ac, 0.0f)) * p;            // acos(|c|)
    float acosc = (c >= 0.0f) ? r : (3.14159265358979f - r);
    float theta = 2.0f * acosc;
    return theta * theta;
}

// One tile-array stage: CH global_load_lds_dwordx4, NT aux bit (2).
// LDS dest is wave-uniform base + lane*16 (hence tid & ~63); global src is
// per-lane. Fire-and-forget: no VGPR return slot occupied.
__device__ __forceinline__ void stage_tile(const float4* __restrict__ g,
                                           float4* lds_arr, int t, int tid) {
    #pragma unroll
    for (int c = 0; c < CH; c++) {
        const float4* gp = g + (size_t)t * TQ + c * BLOCK + tid;
        float4* lp = lds_arr + c * BLOCK + (tid & ~63);
        __builtin_amdgcn_global_load_lds(
            (const __attribute__((address_space(1))) void*)gp,
            (__attribute__((address_space(3))) void*)lp, 16, 0, 2 /*nt*/);
    }
}

// Round 11: test whether the ~3.7 TB/s read cap lives in the VGPR
// writeback/return stage. All prior variants return loads to VGPRs; the 6.5
// TB/s fillBuffer has no return path. global_load_lds streams HBM->LDS with
// no register writeback. Double-buffered: stage tile t+1 while computing t.
// Raw s_barrier + counted vmcnt(4) (NOT __syncthreads, which drains the
// prefetch queue - the documented m97 stall). lgkmcnt(0)+memory before the
// end barrier retires ds_reads before the buffer is overwritten.
__global__ __launch_bounds__(BLOCK) void geo_loss_kernel(
        const float4* __restrict__ a,
        const float4* __restrict__ idd,
        float* __restrict__ partials, int n, int nfull) {
    __shared__ float4 ldsbuf[2][2][TQ];   // [buf][array][elem] = 32 KB
    const int tid = threadIdx.x;
    float acc = 0.0f;

    int t = blockIdx.x;
    int cur = 0;
    if (t < nfull) {
        stage_tile(a,   &ldsbuf[0][0][0], t, tid);
        stage_tile(idd, &ldsbuf[0][1][0], t, tid);   // 4 DMAs in flight
        for (; t < nfull; t += GRID) {
            int tn = t + GRID;                        // block-uniform branch
            if (tn < nfull) {
                stage_tile(a,   &ldsbuf[cur ^ 1][0][0], tn, tid);
                stage_tile(idd, &ldsbuf[cur ^ 1][1][0], tn, tid);
                asm volatile("s_waitcnt vmcnt(4)" ::: "memory"); // tile t done,
            } else {                                             // t+1 in flight
                asm volatile("s_waitcnt vmcnt(0)" ::: "memory");
            }
            __builtin_amdgcn_s_barrier();             // all waves' DMAs landed
            __builtin_amdgcn_sched_barrier(0);
            #pragma unroll
            for (int c = 0; c < CH; c++)
                acc += theta_sq(ldsbuf[cur][0][c * BLOCK + tid],
                                ldsbuf[cur][1][c * BLOCK + tid]);
            asm volatile("s_waitcnt lgkmcnt(0)" ::: "memory"); // reads retired
            __builtin_amdgcn_s_barrier();             // before buf reuse
            cur ^= 1;
        }
    }

    // tail (n - nfull*TQ = 256 elems): guarded direct loads
    for (int idx = nfull * TQ + blockIdx.x * BLOCK + tid; idx < n;
         idx += GRID * BLOCK)
        acc += theta_sq(a[idx], idd[idx]);

    // wave-64 reduction
    #pragma unroll
    for (int off = 32; off > 0; off >>= 1)
        acc += __shfl_down(acc, off, 64);
    __shared__ float smem[BLOCK / 64];
    int lane = tid & 63;
    int wid  = tid >> 6;
    if (lane == 0) smem[wid] = acc;
    __syncthreads();
    if (tid == 0) {
        float s = 0.0f;
        #pragma unroll
        for (int i = 0; i < BLOCK / 64; i++) s += smem[i];
        partials[blockIdx.x] = s;
    }
}

__global__ __launch_bounds__(256) void finalize_kernel(
        const float* __restrict__ partials,
        float* __restrict__ out, int nparts) {
    float acc = 0.0f;
    for (int i = threadIdx.x; i < nparts; i += 256)
        acc += partials[i];
    #pragma unroll
    for (int off = 32; off > 0; off >>= 1)
        acc += __shfl_down(acc, off, 64);
    __shared__ float smem[4];
    int lane = threadIdx.x & 63;
    int wid  = threadIdx.x >> 6;
    if (lane == 0) smem[wid] = acc;
    __syncthreads();
    if (threadIdx.x == 0)
        out[0] = sqrtf(smem[0] + smem[1] + smem[2] + smem[3]);
}

extern "C" void kernel_launch(void* const* d_in, const int* in_sizes, int n_in,
                              void* d_out, int out_size, void* d_ws, size_t ws_size,
                              hipStream_t stream) {
    const float4* a   = (const float4*)d_in[0];
    const float4* idd = (const float4*)d_in[1];
    int n = in_sizes[0] / 4;             // 4,000,000 quaternions
    float* ws = (float*)d_ws;

    int nfull = n / TQ;                  // 7812 full tiles (+256 tail elems)
    geo_loss_kernel<<<GRID, BLOCK, 0, stream>>>(a, idd, ws, n, nfull);
    finalize_kernel<<<1, 256, 0, stream>>>(ws, (float*)d_out, GRID);
}

// Round 12
// 136.433 us; speedup vs baseline: 1.0476x; 1.0476x over previous
//
#include <hip/hip_runtime.h>
#include <math.h>

#define BLOCK 256
#define UNROLL 4
#define TILE (BLOCK * UNROLL)     // 1024 elements per tile, contiguous
#define MAX_GRID 2048             // 8 blocks/CU * 256 CUs -> all resident

// clang ext-vector alias: bit-identical to float4, accepted by
// __builtin_nontemporal_load (HIP_vector_type is a struct and is rejected).
typedef float vf4 __attribute__((ext_vector_type(4)));

// theta^2 for rel = qinv(a) * idd.
// rel is (nearly) unit-norm, so atan2(|v|, w) == acos(w / |rel|).
// Hastings acos approx, max abs err ~6.8e-5 rad (tolerance is 2% relative).
__device__ __forceinline__ float theta_sq(vf4 qa, vf4 qb) {
    float w1 = qa.x, x1 = -qa.y, y1 = -qa.z, z1 = -qa.w;
    float w2 = qb.x, x2 = qb.y,  y2 = qb.z,  z2 = qb.w;
    float w  = w1*w2 - (x1*x2 + y1*y2 + z1*z2);
    float vx = w1*x2 + w2*x1 + (y1*z2 - z1*y2);
    float vy = w1*y2 + w2*y1 + (z1*x2 - x1*z2);
    float vz = w1*z2 + w2*z1 + (x1*y2 - y1*x2);
    float nv2 = vx*vx + vy*vy + vz*vz;
    if (nv2 < 1e-12f) {                  // reference small-angle branch (nv < 1e-6)
        float s = 2.0f / w;
        return nv2 * s * s;
    }
    float rn = rsqrtf(w*w + nv2);        // exact normalize (~1.0)
    float c  = w * rn;                   // cos(theta/2) in [-1,1]
    float ac = fabsf(c);
    float p  = ((-0.0187293f*ac + 0.0742610f)*ac - 0.2121144f)*ac + 1.5707288f;
    float r  = sqrtf(fmaxf(1.0f - ac, 0.0f)) * p;            // acos(|c|)
    float acosc = (c >= 0.0f) ? r : (3.14159265358979f - r);
    float theta = 2.0f * acosc;
    return theta * theta;
}

// FINAL (revert to Round-7 champion, 135.3 us total / geo ~34.5 us).
// 11-round experiment ledger on the read path:
//   temporal loads:        ~42 us  (3.07 TB/s) — allocation-throttled
//   + occupancy/launch:    null   (R1)
//   + forced MLP (asm):    null   (R2-R5)
//   NT loads (this file):  ~34.5us (3.7 TB/s) — THE lever (+18%)  [R7]
//   NT + forced MLP:       -2%    (R8)
//   sc1 nt scope bits:     < R7   (R9)
//   mixed temporal/NT:     -4%    (R10)
//   LDS-direct DMA (no VGPR writeback): -6% (R11)
// Conclusion: single shared read-service resource; NT (non-allocating) is
// its fastest mode at ~3.7 TB/s for this 2-stream float4 pattern. Remaining
// timed-region cost is harness-owned (2x268 MB workspace-poison fills).
__global__ __launch_bounds__(BLOCK, 8) void geo_loss_kernel(
        const vf4* __restrict__ a,
        const vf4* __restrict__ idd,
        float* __restrict__ partials, int n, int ntiles) {
    const int tid = threadIdx.x;
    float acc = 0.0f;

    for (int t = blockIdx.x; t < ntiles; t += gridDim.x) {
        const int base = t * TILE + tid;
        if (base + (UNROLL - 1) * BLOCK < n) {
            vf4 qa[UNROLL], qb[UNROLL];
            #pragma unroll
            for (int k = 0; k < UNROLL; k++) {
                qa[k] = __builtin_nontemporal_load(&a[base + k * BLOCK]);
                qb[k] = __builtin_nontemporal_load(&idd[base + k * BLOCK]);
            }
            #pragma unroll
            for (int k = 0; k < UNROLL; k++) acc += theta_sq(qa[k], qb[k]);
        } else {
            for (int k = 0; k < UNROLL; k++) {
                int idx = base + k * BLOCK;
                if (idx < n) acc += theta_sq(a[idx], idd[idx]);
            }
        }
    }

    // wave-64 reduction
    #pragma unroll
    for (int off = 32; off > 0; off >>= 1)
        acc += __shfl_down(acc, off, 64);
    __shared__ float smem[BLOCK / 64];
    int lane = tid & 63;
    int wid  = tid >> 6;
    if (lane == 0) smem[wid] = acc;
    __syncthreads();
    if (tid == 0) {
        float s = 0.0f;
        #pragma unroll
        for (int i = 0; i < BLOCK / 64; i++) s += smem[i];
        partials[blockIdx.x] = s;
    }
}

__global__ __launch_bounds__(256) void finalize_kernel(
        const float* __restrict__ partials,
        float* __restrict__ out, int nparts) {
    float acc = 0.0f;
    for (int i = threadIdx.x; i < nparts; i += 256)
        acc += partials[i];
    #pragma unroll
    for (int off = 32; off > 0; off >>= 1)
        acc += __shfl_down(acc, off, 64);
    __shared__ float smem[4];
    int lane = threadIdx.x & 63;
    int wid  = threadIdx.x >> 6;
    if (lane == 0) smem[wid] = acc;
    __syncthreads();
    if (threadIdx.x == 0)
        out[0] = sqrtf(smem[0] + smem[1] + smem[2] + smem[3]);
}

extern "C" void kernel_launch(void* const* d_in, const int* in_sizes, int n_in,
                              void* d_out, int out_size, void* d_ws, size_t ws_size,
                              hipStream_t stream) {
    const vf4* a   = (const vf4*)d_in[0];
    const vf4* idd = (const vf4*)d_in[1];
    int n = in_sizes[0] / 4;             // 4,000,000 quaternions
    float* ws = (float*)d_ws;

    int ntiles = (n + TILE - 1) / TILE;  // 3907
    int grid   = ntiles < MAX_GRID ? ntiles : MAX_GRID;
    geo_loss_kernel<<<grid, BLOCK, 0, stream>>>(a, idd, ws, n, ntiles);
    finalize_kernel<<<1, 256, 0, stream>>>(ws, (float*)d_out, grid);
}